// Round 19
// baseline (229.600 us; speedup 1.0000x reference)
//
#include <hip/hip_runtime.h>

#define B_    1024
#define T_    2048
#define SEAS_ 24
#define C_    6
#define W_    1977   // T - OS - IS + 1
#define SFW_  2096   // seas_full width
#define CH_   120    // chunk length (multiple of 24)
#define NCH_  17     // chunks c=0..15: 120 steps; c=16: 127 steps

typedef float vf2 __attribute__((ext_vector_type(2)));

__device__ __forceinline__ float frcp(float x) { return __builtin_amdgcn_rcpf(x); }
__device__ __forceinline__ float getc(const float4& v, int c) {
    return c == 0 ? v.x : c == 1 ? v.y : c == 2 ? v.z : v.w;   // c is compile-time
}

// DPP helpers (VALU pipe, ~4-8 cyc dependent latency — not LDS like ds_bpermute).
template <int CTRL>
__device__ __forceinline__ float dpp_z(float v) {              // zero-fill row_shr
    return __int_as_float(__builtin_amdgcn_update_dpp(
        0, __float_as_int(v), CTRL, 0xf, 0xf, true));
}
__device__ __forceinline__ float dpp_bcast15_z(float v) {      // rows 1,3 <- lane15/47
    return __int_as_float(__builtin_amdgcn_update_dpp(
        0, __float_as_int(v), 0x142, 0xa, 0xf, false));
}
__device__ __forceinline__ float readlane_f(float v, int l) {  // l compile-time; SALU
    return __int_as_float(__builtin_amdgcn_readlane(__float_as_int(v), l));
}

// ---------------- Phase 1 block: DPP weighted Kogge-Stone over 24 lanes ----------------
__device__ __forceinline__ void scan_block(
    float xv, float& s_own, float& lev, float lev_a, float seas_b, float omb,
    float p1, float p2, float p4, float p8, float wrow, float myp)
{
    float ar  = lev_a * (xv * frcp(s_own));
    float acc = ar;
    acc = __builtin_fmaf(p1, dpp_z<0x111>(acc), acc);    // row_shr:1
    acc = __builtin_fmaf(p2, dpp_z<0x112>(acc), acc);    // row_shr:2
    acc = __builtin_fmaf(p4, dpp_z<0x114>(acc), acc);    // row_shr:4
    acc = __builtin_fmaf(p8, dpp_z<0x118>(acc), acc);    // row_shr:8
    acc = __builtin_fmaf(wrow, dpp_bcast15_z(acc), acc); // cross-row (lanes 16..23)
    float lv = __builtin_fmaf(myp, lev, acc);            // lev after own step
    float ns = __builtin_fmaf(omb, s_own, seas_b * (xv * frcp(lv)));
    s_own = ns;                                          // lanes >= 24: harmless junk
    lev = readlane_f(lv, 23);                            // block carry (step 23 = slot 0)
}

// ---------------- Phase 1 (MEASUREMENT BUILD: x16 in-kernel repeat) --------------------
// Idempotent: each rep recomputes and rewrites the identical state values. An opaque
// per-rep zero (asm) blocks cross-rep CSE/hoisting so every rep does the full work.
// phase1_per_rep = (dur_us_total - 109.3) / 15.
__global__ __launch_bounds__(64, 1) void scan_phase1(
    const float* __restrict__ x, const float* __restrict__ lev_sms,
    const float* __restrict__ seas_sms, const float* __restrict__ seasonalities,
    const int* __restrict__ idxs, float* __restrict__ state)
{
    int b    = blockIdx.x;                           // one series per wave
    int lane = threadIdx.x;                          // 0..63

    #pragma unroll 1
    for (int rep = 0; rep < 16; ++rep) {
        int zero;                                    // opaque 0, fresh each rep
        asm volatile("v_mov_b32 %0, 0" : "=v"(zero));
        const float* xr = x + (size_t)b * T_ + zero;

        int id = idxs[b + zero];
        float lev_a  = 1.0f / (1.0f + __expf(-lev_sms[id]));
        float seas_b = 1.0f / (1.0f + __expf(-seas_sms[id]));
        float oma = 1.0f - lev_a, omb = 1.0f - seas_b;

        float p1 = oma, p2 = p1 * p1, p4 = p2 * p2, p8 = p4 * p4, p16 = p8 * p8;
        int lp1 = lane + 1;
        float myp = ((lp1 & 1)  ? p1  : 1.0f) * ((lp1 & 2)  ? p2  : 1.0f)
                  * ((lp1 & 4)  ? p4  : 1.0f) * ((lp1 & 8)  ? p8  : 1.0f)
                  * ((lp1 & 16) ? p16 : 1.0f);       // oma^(lane+1)
        int e = lane - 15;
        float wrow = 0.0f;
        if (e > 0) {
            wrow = ((e & 1) ? p1 : 1.0f) * ((e & 2) ? p2 : 1.0f)
                 * ((e & 4) ? p4 : 1.0f) * ((e & 8) ? p8 : 1.0f);   // oma^(lane-15)
        }

        int pos_own = (lane + 1 < 24) ? (lane + 1) : 0;  // lane 23 -> slot 0
        float s_own = 1.0f;
        if (lane < 24) s_own = __expf(seasonalities[id * SEAS_ + pos_own]);

        float s0  = readlane_f(s_own, 23);
        float lev = xr[0] * frcp(s0);                // lev0

        float xA0 = xr[1 +   0 + lane], xA1 = xr[1 +  24 + lane],
              xA2 = xr[1 +  48 + lane], xA3 = xr[1 +  72 + lane],
              xA4 = xr[1 +  96 + lane];
        float xB0 = xr[1 + 120 + lane], xB1 = xr[1 + 144 + lane],
              xB2 = xr[1 + 168 + lane], xB3 = xr[1 + 192 + lane],
              xB4 = xr[1 + 216 + lane];

        for (int g = 0; g < 16; g += 2) {
            int baseA = 1 + 5 * (g + 2) * 24 + lane;
            scan_block(xA0, s_own, lev, lev_a, seas_b, omb, p1, p2, p4, p8, wrow, myp);
            { int t = baseA;      xA0 = xr[t > 2047 ? 2047 : t]; }
            scan_block(xA1, s_own, lev, lev_a, seas_b, omb, p1, p2, p4, p8, wrow, myp);
            { int t = baseA + 24; xA1 = xr[t > 2047 ? 2047 : t]; }
            scan_block(xA2, s_own, lev, lev_a, seas_b, omb, p1, p2, p4, p8, wrow, myp);
            { int t = baseA + 48; xA2 = xr[t > 2047 ? 2047 : t]; }
            scan_block(xA3, s_own, lev, lev_a, seas_b, omb, p1, p2, p4, p8, wrow, myp);
            { int t = baseA + 72; xA3 = xr[t > 2047 ? 2047 : t]; }
            scan_block(xA4, s_own, lev, lev_a, seas_b, omb, p1, p2, p4, p8, wrow, myp);
            { int t = baseA + 96; xA4 = xr[t > 2047 ? 2047 : t]; }
            {   float* st = state + ((size_t)g * B_ + b) * 25;       // t = 120(g+1)
                if (lane < 24) st[pos_own] = s_own;
                if (lane == 24) st[24] = lev;
            }
            int baseB = 1 + 5 * (g + 3) * 24 + lane;
            scan_block(xB0, s_own, lev, lev_a, seas_b, omb, p1, p2, p4, p8, wrow, myp);
            { int t = baseB;      xB0 = xr[t > 2047 ? 2047 : t]; }
            scan_block(xB1, s_own, lev, lev_a, seas_b, omb, p1, p2, p4, p8, wrow, myp);
            { int t = baseB + 24; xB1 = xr[t > 2047 ? 2047 : t]; }
            scan_block(xB2, s_own, lev, lev_a, seas_b, omb, p1, p2, p4, p8, wrow, myp);
            { int t = baseB + 48; xB2 = xr[t > 2047 ? 2047 : t]; }
            scan_block(xB3, s_own, lev, lev_a, seas_b, omb, p1, p2, p4, p8, wrow, myp);
            { int t = baseB + 72; xB3 = xr[t > 2047 ? 2047 : t]; }
            scan_block(xB4, s_own, lev, lev_a, seas_b, omb, p1, p2, p4, p8, wrow, myp);
            { int t = baseB + 96; xB4 = xr[t > 2047 ? 2047 : t]; }
            {   float* st = state + ((size_t)(g + 1) * B_ + b) * 25; // t = 120(g+2)
                if (lane < 24) st[pos_own] = s_own;
                if (lane == 24) st[24] = lev;
            }
        }
    }
}

// One 24-step block (steps t = 24k+1 .. 24k+24; element e = j+1). ILP-exposed.
template <bool STORE>
__device__ __forceinline__ void es_block24(
    const float4* __restrict__ xv, float* __restrict__ s,
    float lev_a, float oma, float seas_b, float omb, float& lev,
    float* __restrict__ levp, float* __restrict__ nsp)
{
    float ar[24], lv[24];
    #pragma unroll
    for (int j = 0; j < 24; ++j) {
        const int e = j + 1, pos = (j + 1 < 24) ? (j + 1) : 0;
        ar[j] = lev_a * (getc(xv[e >> 2], e & 3) * frcp(s[pos]));
    }
    #pragma unroll
    for (int j = 0; j < 24; ++j) {                   // serial lev chain
        lev = __builtin_fmaf(oma, lev, ar[j]);
        lv[j] = lev;
    }
    #pragma unroll
    for (int j = 0; j < 24; ++j) {                   // independent seasonal updates
        const int e = j + 1, pos = (j + 1 < 24) ? (j + 1) : 0;
        float xi = getc(xv[e >> 2], e & 3);
        float ns = __builtin_fmaf(omb, s[pos], seas_b * (xi * frcp(lv[j])));
        s[pos] = ns;
        if (STORE) {
            levp[(size_t)j * B_] = lv[j];
            nsp[(size_t)j * B_]  = ns;
        }
    }
}

// ---------------- Phase 2: 17 exact chunks in parallel, coalesced heavy stores ---------
__global__ __launch_bounds__(64, 1) void scan_phase2(
    const float* __restrict__ x, const float* __restrict__ lev_sms,
    const float* __restrict__ seas_sms, const float* __restrict__ seasonalities,
    const int* __restrict__ idxs, const float* __restrict__ state,
    float* __restrict__ levT, float* __restrict__ nsT)
{
    int b = blockIdx.x * 64 + threadIdx.x;
    int c = blockIdx.y;
    const float4* xr4 = (const float4*)(x + (size_t)b * T_);

    int id = idxs[b];
    float lev_a  = 1.0f / (1.0f + __expf(-lev_sms[id]));
    float seas_b = 1.0f / (1.0f + __expf(-seas_sms[id]));
    float oma = 1.0f - lev_a, omb = 1.0f - seas_b;

    float s[SEAS_];
    float lev;
    if (c == 0) {
        #pragma unroll
        for (int j = 0; j < SEAS_; ++j) s[j] = __expf(seasonalities[id * SEAS_ + j]);
        lev = getc(xr4[0], 0) * frcp(s[0]);              // lev0
        levT[b] = lev;                                   // row 0
    } else {
        const float* st = state + ((size_t)(c - 1) * B_ + b) * 25;
        #pragma unroll
        for (int j = 0; j < SEAS_; ++j) s[j] = st[j];
        lev = st[24];
    }

    float4 xv[7], xn[7];
    const float4* base0 = xr4 + 30 * c;                  // t = 120c ..
    #pragma unroll
    for (int q = 0; q < 7; ++q) xv[q] = base0[q];

    float* levp = levT + (size_t)(120 * c + 1) * B_ + b;
    float* nsp  = nsT  + (size_t)(120 * c) * B_ + b;

    #pragma unroll
    for (int kb = 0; kb < 5; ++kb) {                     // 5 blocks of 24 steps
        const float4* nb = xr4 + 30 * c + 6 * (kb + 1);
        if (c == NCH_ - 1 && kb == 4) {                  // next base 510: only 2 in-bounds
            xn[0] = nb[0]; xn[1] = nb[1];
        } else {
            #pragma unroll
            for (int q = 0; q < 7; ++q) xn[q] = nb[q];
        }
        es_block24<true>(xv, s, lev_a, oma, seas_b, omb, lev, levp, nsp);
        levp += (size_t)24 * B_;
        nsp  += (size_t)24 * B_;
        #pragma unroll
        for (int q = 0; q < 7; ++q) xv[q] = xn[q];
    }
    if (c == NCH_ - 1) {                                 // tail t = 2041..2047
        #pragma unroll
        for (int j = 0; j < 7; ++j) {
            const int e = j + 1, pos = j + 1;
            float xi    = getc(xv[e >> 2], e & 3);
            float ratio = xi * frcp(s[pos]);
            float nl    = __builtin_fmaf(oma, lev, lev_a * ratio);
            float ns    = __builtin_fmaf(omb, s[pos], seas_b * (xi * frcp(nl)));
            s[pos] = ns;
            lev = nl;
            levp[0] = nl;  levp += B_;
            nsp[0]  = ns;  nsp  += B_;
        }
    }
}

// ---------------- transpose levT[t][b] -> out_levs[b][t] ----------------
__global__ __launch_bounds__(256) void transposeL_kernel(
    const float* __restrict__ levT, float* __restrict__ out)
{
    __shared__ float tile[32][33];
    int bt = blockIdx.y * 32;
    int bb = blockIdx.x * 32;
    int tx = threadIdx.x, ty = threadIdx.y;          // (32, 8)
    #pragma unroll
    for (int r = 0; r < 32; r += 8)
        tile[ty + r][tx] = levT[(size_t)(bt + ty + r) * B_ + bb + tx];
    __syncthreads();
    #pragma unroll
    for (int r = 0; r < 32; r += 8)
        out[(size_t)(bb + ty + r) * T_ + bt + tx] = tile[tx][ty + r];
}

// ---------------- transpose nsT -> out_seas[b][u], u in [0, 2096) ----------------
__global__ __launch_bounds__(256) void transposeS_kernel(
    const float* __restrict__ nsT, const float* __restrict__ seasonalities,
    const int* __restrict__ idxs, float* __restrict__ out_seas)
{
    __shared__ float tile[32][33];
    int bu = blockIdx.y * 32;
    int bb = blockIdx.x * 32;
    int tx = threadIdx.x, ty = threadIdx.y;
    int id = idxs[bb + tx];
    #pragma unroll
    for (int r = 0; r < 32; r += 8) {
        int u = bu + ty + r;
        if (u < 25) {
            tile[ty + r][tx] = __expf(seasonalities[id * SEAS_ + (u < 24 ? u : 0)]);
        } else if (u < SFW_) {
            int rr = u - 25 - (u >= 2072 ? 24 : 0);
            tile[ty + r][tx] = nsT[(size_t)rr * B_ + bb + tx];
        }
    }
    __syncthreads();
    #pragma unroll
    for (int r = 0; r < 32; r += 8) {
        int u = bu + tx;
        if (u < SFW_)
            out_seas[(size_t)(bb + ty + r) * SFW_ + u] = tile[tx][ty + r];
    }
}

// ---------------- window materialization (243 MB, write-bound) ----------------
__global__ __launch_bounds__(256) void win_kernel(
    const float* __restrict__ x, const float* __restrict__ levs,
    const float* __restrict__ seasF, const float* __restrict__ info_cat,
    vf2* __restrict__ out)
{
    int w  = blockIdx.y;
    int e2 = blockIdx.x * 256 + threadIdx.x;         // 0..15359 == B*15
    int b  = e2 / 15;
    int j  = e2 - b * 15;
    vf2 v;
    if (j < 12) {
        float inv = frcp(levs[b * T_ + w + 23]);
        int t = w + 2 * j;
        float sa = seasF[b * SFW_ + t];
        float sb = seasF[b * SFW_ + t + 1];
        v.x = x[b * T_ + t]     * frcp(sa) * inv;
        v.y = x[b * T_ + t + 1] * frcp(sb) * inv;
    } else {
        int c = 2 * (j - 12);
        v.x = info_cat[b * C_ + c];
        v.y = info_cat[b * C_ + c + 1];
    }
    __builtin_nontemporal_store(v, &out[(size_t)w * 15360 + e2]);
}

// ---------------- msld: mean_b (logL[i+2] - 2 logL[i+1] + logL[i])^2 ----------------
__global__ __launch_bounds__(256) void msld_kernel(
    const float* __restrict__ levT, float* __restrict__ out)
{
    int i = blockIdx.x;                              // 0..2045
    const float* r0 = levT + (size_t)i * B_;
    float ssum = 0.0f;
    #pragma unroll
    for (int r = 0; r < 4; ++r) {
        int b = threadIdx.x + 256 * r;
        float l0 = __logf(r0[b]);
        float l1 = __logf(r0[b + B_]);
        float l2 = __logf(r0[b + 2 * B_]);
        float d  = l2 - 2.0f * l1 + l0;
        ssum = __builtin_fmaf(d, d, ssum);
    }
    #pragma unroll
    for (int off = 32; off > 0; off >>= 1) ssum += __shfl_down(ssum, off);
    __shared__ float partial[4];
    int wid = threadIdx.x >> 6;
    if ((threadIdx.x & 63) == 0) partial[wid] = ssum;
    __syncthreads();
    if (threadIdx.x == 0)
        out[i] = (partial[0] + partial[1] + partial[2] + partial[3]) * (1.0f / 1024.0f);
}

extern "C" void kernel_launch(void* const* d_in, const int* in_sizes, int n_in,
                              void* d_out, int out_size, void* d_ws, size_t ws_size,
                              hipStream_t stream)
{
    const float* train    = (const float*)d_in[0];
    const float* info_cat = (const float*)d_in[3];
    const float* lev_sms  = (const float*)d_in[4];
    const float* seas_sms = (const float*)d_in[5];
    const float* seasonal = (const float*)d_in[6];
    const int*   idxs     = (const int*)d_in[7];

    float* out      = (float*)d_out;
    float* out_ib   = out;                               // W*B*30
    float* out_levs = out + (size_t)W_ * B_ * 30;        // B*2048
    float* out_seas = out_levs + (size_t)B_ * T_;        // B*2096
    float* out_msld = out_seas + (size_t)B_ * SFW_;      // 2046

    float* ws   = (float*)d_ws;
    float* levT = ws;                                    // 2048*1024 floats
    float* nsT  = ws + (size_t)T_ * B_;                  // 2047*1024 floats

    float* state = out_ib;                               // 16*1024*25 floats (1.6 MB)

    scan_phase1<<<B_, 64, 0, stream>>>(train, lev_sms, seas_sms, seasonal, idxs, state);

    scan_phase2<<<dim3(B_ / 64, NCH_), 64, 0, stream>>>(train, lev_sms, seas_sms,
                                                        seasonal, idxs, state, levT, nsT);

    msld_kernel<<<2046, 256, 0, stream>>>(levT, out_msld);

    dim3 tb(32, 8);
    transposeL_kernel<<<dim3(B_ / 32, T_ / 32), tb, 0, stream>>>(levT, out_levs);
    transposeS_kernel<<<dim3(B_ / 32, (SFW_ + 31) / 32), tb, 0, stream>>>(
        nsT, seasonal, idxs, out_seas);

    dim3 g2(60, W_);
    win_kernel<<<g2, 256, 0, stream>>>(train, out_levs, out_seas, info_cat, (vf2*)out_ib);
}

// Round 20
// 107.711 us; speedup vs baseline: 2.1316x; 2.1316x over previous
//
#include <hip/hip_runtime.h>

#define B_    1024
#define T_    2048
#define SEAS_ 24
#define C_    6
#define W_    1977   // T - OS - IS + 1
#define SFW_  2096   // seas_full width
#define NCH_  17     // chunks c=0..15: 120 steps; c=16: 127 steps

typedef float vf2 __attribute__((ext_vector_type(2)));

__device__ __forceinline__ float frcp(float x) { return __builtin_amdgcn_rcpf(x); }
__device__ __forceinline__ float getc(const float4& v, int c) {
    return c == 0 ? v.x : c == 1 ? v.y : c == 2 ? v.z : v.w;   // c is compile-time
}

template <int CTRL>
__device__ __forceinline__ float dpp_z(float v) {              // zero-fill row_shr
    return __int_as_float(__builtin_amdgcn_update_dpp(
        0, __float_as_int(v), CTRL, 0xf, 0xf, true));
}
__device__ __forceinline__ float dpp_bcast15_z(float v) {      // rows 1,3 <- lane15/47
    return __int_as_float(__builtin_amdgcn_update_dpp(
        0, __float_as_int(v), 0x142, 0xa, 0xf, false));
}
__device__ __forceinline__ float readlane_f(float v, int l) {  // l compile-time; SALU
    return __int_as_float(__builtin_amdgcn_readlane(__float_as_int(v), l));
}

// ---------------- Phase 1 block: DPP weighted Kogge-Stone over 24 lanes ----------------
__device__ __forceinline__ void scan_block(
    float xv, float& s_own, float& lev, float lev_a, float seas_b, float omb,
    float p1, float p2, float p4, float p8, float wrow, float myp)
{
    float ar  = lev_a * (xv * frcp(s_own));
    float acc = ar;
    acc = __builtin_fmaf(p1, dpp_z<0x111>(acc), acc);    // row_shr:1
    acc = __builtin_fmaf(p2, dpp_z<0x112>(acc), acc);    // row_shr:2
    acc = __builtin_fmaf(p4, dpp_z<0x114>(acc), acc);    // row_shr:4
    acc = __builtin_fmaf(p8, dpp_z<0x118>(acc), acc);    // row_shr:8
    acc = __builtin_fmaf(wrow, dpp_bcast15_z(acc), acc); // cross-row (lanes 16..23)
    float lv = __builtin_fmaf(myp, lev, acc);            // lev after own step
    float ns = __builtin_fmaf(omb, s_own, seas_b * (xv * frcp(lv)));
    s_own = ns;                                          // lanes >= 24: harmless junk
    lev = readlane_f(lv, 23);                            // block carry (step 23 = slot 0)
}

// ---------------- Phase 1: slot-parallel DPP scan (one wave/series), ~8 us -------------
__global__ __launch_bounds__(64, 1) void scan_phase1(
    const float* __restrict__ x, const float* __restrict__ lev_sms,
    const float* __restrict__ seas_sms, const float* __restrict__ seasonalities,
    const int* __restrict__ idxs, float* __restrict__ state)
{
    int b    = blockIdx.x;
    int lane = threadIdx.x;
    const float* xr = x + (size_t)b * T_;

    int id = idxs[b];
    float lev_a  = 1.0f / (1.0f + __expf(-lev_sms[id]));
    float seas_b = 1.0f / (1.0f + __expf(-seas_sms[id]));
    float oma = 1.0f - lev_a, omb = 1.0f - seas_b;

    float p1 = oma, p2 = p1 * p1, p4 = p2 * p2, p8 = p4 * p4, p16 = p8 * p8;
    int lp1 = lane + 1;
    float myp = ((lp1 & 1)  ? p1  : 1.0f) * ((lp1 & 2)  ? p2  : 1.0f)
              * ((lp1 & 4)  ? p4  : 1.0f) * ((lp1 & 8)  ? p8  : 1.0f)
              * ((lp1 & 16) ? p16 : 1.0f);           // oma^(lane+1)
    int e = lane - 15;
    float wrow = 0.0f;
    if (e > 0) {
        wrow = ((e & 1) ? p1 : 1.0f) * ((e & 2) ? p2 : 1.0f)
             * ((e & 4) ? p4 : 1.0f) * ((e & 8) ? p8 : 1.0f);   // oma^(lane-15)
    }

    int pos_own = (lane + 1 < 24) ? (lane + 1) : 0;
    float s_own = 1.0f;
    if (lane < 24) s_own = __expf(seasonalities[id * SEAS_ + pos_own]);

    float s0  = readlane_f(s_own, 23);
    float lev = xr[0] * frcp(s0);                    // lev0

    float xA0 = xr[1 +   0 + lane], xA1 = xr[1 +  24 + lane], xA2 = xr[1 +  48 + lane],
          xA3 = xr[1 +  72 + lane], xA4 = xr[1 +  96 + lane];
    float xB0 = xr[1 + 120 + lane], xB1 = xr[1 + 144 + lane], xB2 = xr[1 + 168 + lane],
          xB3 = xr[1 + 192 + lane], xB4 = xr[1 + 216 + lane];

    for (int g = 0; g < 16; g += 2) {
        int baseA = 1 + 5 * (g + 2) * 24 + lane;
        scan_block(xA0, s_own, lev, lev_a, seas_b, omb, p1, p2, p4, p8, wrow, myp);
        { int t = baseA;      xA0 = xr[t > 2047 ? 2047 : t]; }
        scan_block(xA1, s_own, lev, lev_a, seas_b, omb, p1, p2, p4, p8, wrow, myp);
        { int t = baseA + 24; xA1 = xr[t > 2047 ? 2047 : t]; }
        scan_block(xA2, s_own, lev, lev_a, seas_b, omb, p1, p2, p4, p8, wrow, myp);
        { int t = baseA + 48; xA2 = xr[t > 2047 ? 2047 : t]; }
        scan_block(xA3, s_own, lev, lev_a, seas_b, omb, p1, p2, p4, p8, wrow, myp);
        { int t = baseA + 72; xA3 = xr[t > 2047 ? 2047 : t]; }
        scan_block(xA4, s_own, lev, lev_a, seas_b, omb, p1, p2, p4, p8, wrow, myp);
        { int t = baseA + 96; xA4 = xr[t > 2047 ? 2047 : t]; }
        {   float* st = state + ((size_t)g * B_ + b) * 25;       // t = 120(g+1)
            if (lane < 24) st[pos_own] = s_own;
            if (lane == 24) st[24] = lev;
        }
        int baseB = 1 + 5 * (g + 3) * 24 + lane;
        scan_block(xB0, s_own, lev, lev_a, seas_b, omb, p1, p2, p4, p8, wrow, myp);
        { int t = baseB;      xB0 = xr[t > 2047 ? 2047 : t]; }
        scan_block(xB1, s_own, lev, lev_a, seas_b, omb, p1, p2, p4, p8, wrow, myp);
        { int t = baseB + 24; xB1 = xr[t > 2047 ? 2047 : t]; }
        scan_block(xB2, s_own, lev, lev_a, seas_b, omb, p1, p2, p4, p8, wrow, myp);
        { int t = baseB + 48; xB2 = xr[t > 2047 ? 2047 : t]; }
        scan_block(xB3, s_own, lev, lev_a, seas_b, omb, p1, p2, p4, p8, wrow, myp);
        { int t = baseB + 72; xB3 = xr[t > 2047 ? 2047 : t]; }
        scan_block(xB4, s_own, lev, lev_a, seas_b, omb, p1, p2, p4, p8, wrow, myp);
        { int t = baseB + 96; xB4 = xr[t > 2047 ? 2047 : t]; }
        {   float* st = state + ((size_t)(g + 1) * B_ + b) * 25; // t = 120(g+2)
            if (lane < 24) st[pos_own] = s_own;
            if (lane == 24) st[24] = lev;
        }
    }
}

// One 24-step block (steps t = 24k+1 .. 24k+24; element e = j+1). ILP-exposed.
template <bool STORE>
__device__ __forceinline__ void es_block24(
    const float4* __restrict__ xv, float* __restrict__ s,
    float lev_a, float oma, float seas_b, float omb, float& lev,
    float* __restrict__ levp, float* __restrict__ nsp)
{
    float ar[24], lv[24];
    #pragma unroll
    for (int j = 0; j < 24; ++j) {
        const int e = j + 1, pos = (j + 1 < 24) ? (j + 1) : 0;
        ar[j] = lev_a * (getc(xv[e >> 2], e & 3) * frcp(s[pos]));
    }
    #pragma unroll
    for (int j = 0; j < 24; ++j) {                   // serial lev chain
        lev = __builtin_fmaf(oma, lev, ar[j]);
        lv[j] = lev;
    }
    #pragma unroll
    for (int j = 0; j < 24; ++j) {                   // independent seasonal updates
        const int e = j + 1, pos = (j + 1 < 24) ? (j + 1) : 0;
        float xi = getc(xv[e >> 2], e & 3);
        float ns = __builtin_fmaf(omb, s[pos], seas_b * (xi * frcp(lv[j])));
        s[pos] = ns;
        if (STORE) {
            levp[(size_t)j * B_] = lv[j];
            nsp[(size_t)j * B_]  = ns;
        }
    }
}

// ---------------- Phase 2: 17 exact chunks in parallel, coalesced heavy stores ---------
__global__ __launch_bounds__(64, 1) void scan_phase2(
    const float* __restrict__ x, const float* __restrict__ lev_sms,
    const float* __restrict__ seas_sms, const float* __restrict__ seasonalities,
    const int* __restrict__ idxs, const float* __restrict__ state,
    float* __restrict__ levT, float* __restrict__ nsT)
{
    int b = blockIdx.x * 64 + threadIdx.x;
    int c = blockIdx.y;
    const float4* xr4 = (const float4*)(x + (size_t)b * T_);

    int id = idxs[b];
    float lev_a  = 1.0f / (1.0f + __expf(-lev_sms[id]));
    float seas_b = 1.0f / (1.0f + __expf(-seas_sms[id]));
    float oma = 1.0f - lev_a, omb = 1.0f - seas_b;

    float s[SEAS_];
    float lev;
    if (c == 0) {
        #pragma unroll
        for (int j = 0; j < SEAS_; ++j) s[j] = __expf(seasonalities[id * SEAS_ + j]);
        lev = getc(xr4[0], 0) * frcp(s[0]);              // lev0
        levT[b] = lev;                                   // row 0
    } else {
        const float* st = state + ((size_t)(c - 1) * B_ + b) * 25;
        #pragma unroll
        for (int j = 0; j < SEAS_; ++j) s[j] = st[j];
        lev = st[24];
    }

    float4 xv[7], xn[7];
    const float4* base0 = xr4 + 30 * c;                  // t = 120c ..
    #pragma unroll
    for (int q = 0; q < 7; ++q) xv[q] = base0[q];

    float* levp = levT + (size_t)(120 * c + 1) * B_ + b;
    float* nsp  = nsT  + (size_t)(120 * c) * B_ + b;

    #pragma unroll
    for (int kb = 0; kb < 5; ++kb) {                     // 5 blocks of 24 steps
        const float4* nb = xr4 + 30 * c + 6 * (kb + 1);
        if (c == NCH_ - 1 && kb == 4) {                  // next base 510: only 2 in-bounds
            xn[0] = nb[0]; xn[1] = nb[1];
        } else {
            #pragma unroll
            for (int q = 0; q < 7; ++q) xn[q] = nb[q];
        }
        es_block24<true>(xv, s, lev_a, oma, seas_b, omb, lev, levp, nsp);
        levp += (size_t)24 * B_;
        nsp  += (size_t)24 * B_;
        #pragma unroll
        for (int q = 0; q < 7; ++q) xv[q] = xn[q];
    }
    if (c == NCH_ - 1) {                                 // tail t = 2041..2047
        #pragma unroll
        for (int j = 0; j < 7; ++j) {
            const int e = j + 1, pos = j + 1;
            float xi    = getc(xv[e >> 2], e & 3);
            float ratio = xi * frcp(s[pos]);
            float nl    = __builtin_fmaf(oma, lev, lev_a * ratio);
            float ns    = __builtin_fmaf(omb, s[pos], seas_b * (xi * frcp(nl)));
            s[pos] = ns;
            lev = nl;
            levp[0] = nl;  levp += B_;
            nsp[0]  = ns;  nsp  += B_;
        }
    }
}

// ---------------- aux: fused transposeL + transposeS (blockIdx.z role) -----------------
__global__ __launch_bounds__(256) void aux_kernel(
    const float* __restrict__ levT, const float* __restrict__ nsT,
    const float* __restrict__ seasonalities, const int* __restrict__ idxs,
    float* __restrict__ out_levs, float* __restrict__ out_seas)
{
    int tx = threadIdx.x, ty = threadIdx.y;          // (32, 8)
    __shared__ float tile[32][33];
    if (blockIdx.z == 0) {                           // transpose levT -> out_levs
        if (blockIdx.y >= T_ / 32) return;
        int bt = blockIdx.y * 32;
        int bb = blockIdx.x * 32;
        #pragma unroll
        for (int r = 0; r < 32; r += 8)
            tile[ty + r][tx] = levT[(size_t)(bt + ty + r) * B_ + bb + tx];
        __syncthreads();
        #pragma unroll
        for (int r = 0; r < 32; r += 8)
            out_levs[(size_t)(bb + ty + r) * T_ + bt + tx] = tile[tx][ty + r];
    } else {                                         // nsT/head -> out_seas
        int bu = blockIdx.y * 32;
        int bb = blockIdx.x * 32;
        int id = idxs[bb + tx];
        #pragma unroll
        for (int r = 0; r < 32; r += 8) {
            int u = bu + ty + r;
            if (u < 25) {
                tile[ty + r][tx] = __expf(seasonalities[id * SEAS_ + (u < 24 ? u : 0)]);
            } else if (u < SFW_) {
                int rr = u - 25 - (u >= 2072 ? 24 : 0);
                tile[ty + r][tx] = nsT[(size_t)rr * B_ + bb + tx];
            }
        }
        __syncthreads();
        #pragma unroll
        for (int r = 0; r < 32; r += 8) {
            int u = bu + tx;
            if (u < SFW_)
                out_seas[(size_t)(bb + ty + r) * SFW_ + u] = tile[tx][ty + r];
        }
    }
}

// ---------------- mega: win (243 MB, write-bound) + msld, by linear block id -----------
// win blocks read out_levs/out_seas (prior aux launch) and x; msld reads levT.
__global__ __launch_bounds__(256) void mega_kernel(
    const float* __restrict__ x, const float* __restrict__ levs,
    const float* __restrict__ seasF, const float* __restrict__ info_cat,
    const float* __restrict__ levT, vf2* __restrict__ out,
    float* __restrict__ out_msld)
{
    int bid = blockIdx.x;
    if (bid < 60 * W_) {                             // ---------------- win role
        int w  = bid / 60;
        int e2 = (bid - w * 60) * 256 + threadIdx.x; // 0..15359 == B*15
        int b  = e2 / 15;
        int j  = e2 - b * 15;
        vf2 v;
        if (j < 12) {
            float inv = frcp(levs[b * T_ + w + 23]);
            int t = w + 2 * j;
            float sa = seasF[b * SFW_ + t];
            float sb = seasF[b * SFW_ + t + 1];
            v.x = x[b * T_ + t]     * frcp(sa) * inv;
            v.y = x[b * T_ + t + 1] * frcp(sb) * inv;
        } else {
            int c = 2 * (j - 12);
            v.x = info_cat[b * C_ + c];
            v.y = info_cat[b * C_ + c + 1];
        }
        __builtin_nontemporal_store(v, &out[(size_t)w * 15360 + e2]);
    } else {                                         // ---------------- msld role
        int i = bid - 60 * W_;                       // 0..2045
        const float* r0 = levT + (size_t)i * B_;
        float ssum = 0.0f;
        #pragma unroll
        for (int r = 0; r < 4; ++r) {
            int b = threadIdx.x + 256 * r;
            float l0 = __logf(r0[b]);
            float l1 = __logf(r0[b + B_]);
            float l2 = __logf(r0[b + 2 * B_]);
            float d  = l2 - 2.0f * l1 + l0;
            ssum = __builtin_fmaf(d, d, ssum);
        }
        #pragma unroll
        for (int off = 32; off > 0; off >>= 1) ssum += __shfl_down(ssum, off);
        __shared__ float partial[4];
        int wid = threadIdx.x >> 6;
        if ((threadIdx.x & 63) == 0) partial[wid] = ssum;
        __syncthreads();
        if (threadIdx.x == 0)
            out_msld[i] = (partial[0] + partial[1] + partial[2] + partial[3])
                          * (1.0f / 1024.0f);
    }
}

extern "C" void kernel_launch(void* const* d_in, const int* in_sizes, int n_in,
                              void* d_out, int out_size, void* d_ws, size_t ws_size,
                              hipStream_t stream)
{
    const float* train    = (const float*)d_in[0];
    const float* info_cat = (const float*)d_in[3];
    const float* lev_sms  = (const float*)d_in[4];
    const float* seas_sms = (const float*)d_in[5];
    const float* seasonal = (const float*)d_in[6];
    const int*   idxs     = (const int*)d_in[7];

    float* out      = (float*)d_out;
    float* out_ib   = out;                               // W*B*30
    float* out_levs = out + (size_t)W_ * B_ * 30;        // B*2048
    float* out_seas = out_levs + (size_t)B_ * T_;        // B*2096
    float* out_msld = out_seas + (size_t)B_ * SFW_;      // 2046

    float* ws   = (float*)d_ws;
    float* levT = ws;                                    // 2048*1024 floats
    float* nsT  = ws + (size_t)T_ * B_;                  // 2047*1024 floats

    // Exact boundary states in the head of out_ib: written by phase1, read by phase2,
    // later overwritten by mega's win blocks (stream-ordered, race-free).
    float* state = out_ib;                               // 16*1024*25 floats (1.6 MB)

    scan_phase1<<<B_, 64, 0, stream>>>(train, lev_sms, seas_sms, seasonal, idxs, state);

    scan_phase2<<<dim3(B_ / 64, NCH_), 64, 0, stream>>>(train, lev_sms, seas_sms,
                                                        seasonal, idxs, state, levT, nsT);

    aux_kernel<<<dim3(32, 66, 2), dim3(32, 8), 0, stream>>>(
        levT, nsT, seasonal, idxs, out_levs, out_seas);

    mega_kernel<<<60 * W_ + 2046, 256, 0, stream>>>(
        train, out_levs, out_seas, info_cat, levT, (vf2*)out_ib, out_msld);
}